// Round 13
// baseline (953.272 us; speedup 1.0000x reference)
//
#include <hip/hip_runtime.h>
#include <math.h>

#define BB 64
#define NN 8192
#define LL 64
#define KK 20
#define TILE 128
#define NT 4        // tiles per block
#define CHUNKS 16   // blocks per batch entry: CHUNKS*NT*TILE == NN (1024 blocks = 4/CU)
#define ZSB 72      // mhl row stride (ushorts)
#define ZTS 136     // zT row stride (ushorts): 272 B
#define PTTS 136    // ptT row stride (ushorts)
#define NSS 68      // Newton-Schulz matrix stride (floats)

typedef float f32x4 __attribute__((ext_vector_type(4)));
typedef short s16x8 __attribute__((ext_vector_type(8)));

#define MFMA_BF16 __builtin_amdgcn_mfma_f32_16x16x32_bf16

__device__ __forceinline__ unsigned short f2bf(float f) {   // RNE fp32->bf16
    unsigned int u = __float_as_uint(f);
    u += 0x7fffu + ((u >> 16) & 1u);
    return (unsigned short)(u >> 16);
}
__device__ __forceinline__ float bf2f(unsigned short h) {
    return __uint_as_float(((unsigned int)h) << 16);
}

// ---------------------------------------------------------------------------
// ws layout (floats): IA @0, M @4096, bias @8192, nk @9472, macc @10752,
// cnt(int) @92672. Requires ws_size >= 370,944 B.
// ---------------------------------------------------------------------------

// IA = I - A ; M = inv(S), S = I + IA·IAᵀ, Newton-Schulz (8 iters, SPD).
__global__ __launch_bounds__(256) void k_setup(const float* __restrict__ A,
                                               float* __restrict__ IA,
                                               float* __restrict__ M) {
    __shared__ __align__(16) float sS[64][NSS];
    __shared__ __align__(16) float sXa[64][NSS];
    __shared__ __align__(16) float sXb[64][NSS];
    __shared__ __align__(16) float sT[64][NSS];   // iaT during build, then T
    __shared__ float rowsum[64];
    __shared__ float alpha_s;
    int t = threadIdx.x;
    int r0 = (t >> 4) << 2;
    int c0 = (t & 15) << 2;

    for (int i = t; i < 4096; i += 256) {
        int r = i >> 6, c = i & 63;
        float v = (r == c ? 1.0f : 0.0f) - A[i];
        IA[i] = v;
        sT[c][r] = v;
    }
    __syncthreads();
    {
        float s[4][4];
        #pragma unroll
        for (int a = 0; a < 4; ++a)
            #pragma unroll
            for (int b = 0; b < 4; ++b) s[a][b] = 0.f;
        #pragma unroll 4
        for (int l = 0; l < 64; ++l) {
            float4 u = *(const float4*)&sT[l][r0];
            float4 v = *(const float4*)&sT[l][c0];
            float uu[4] = {u.x, u.y, u.z, u.w};
            float vv[4] = {v.x, v.y, v.z, v.w};
            #pragma unroll
            for (int a = 0; a < 4; ++a)
                #pragma unroll
                for (int b = 0; b < 4; ++b) s[a][b] += uu[a] * vv[b];
        }
        #pragma unroll
        for (int a = 0; a < 4; ++a) {
            int r = r0 + a;
            float4 w;
            w.x = s[a][0] + (r == c0 + 0 ? 1.f : 0.f);
            w.y = s[a][1] + (r == c0 + 1 ? 1.f : 0.f);
            w.z = s[a][2] + (r == c0 + 2 ? 1.f : 0.f);
            w.w = s[a][3] + (r == c0 + 3 ? 1.f : 0.f);
            *(float4*)&sS[r][c0] = w;
        }
    }
    __syncthreads();
    if (t < 64) {
        float sm = 0.f;
        #pragma unroll 4
        for (int c = 0; c < 64; c += 4) {
            float4 v = *(const float4*)&sS[t][c];
            sm += fabsf(v.x) + fabsf(v.y) + fabsf(v.z) + fabsf(v.w);
        }
        rowsum[t] = sm;
    }
    __syncthreads();
    if (t == 0) {
        float mx = rowsum[0];
        for (int i = 1; i < 64; ++i) mx = fmaxf(mx, rowsum[i]);
        alpha_s = 2.0f / (1.0f + mx);
    }
    __syncthreads();
    float alpha = alpha_s;
    for (int i = t; i < 4096; i += 256) {
        int r = i >> 6, c = i & 63;
        sXa[r][c] = (r == c) ? alpha : 0.f;
    }
    __syncthreads();

    float* X  = &sXa[0][0];
    float* Xn = &sXb[0][0];
    for (int it = 0; it < 8; ++it) {
        {
            float s[4][4];
            #pragma unroll
            for (int a = 0; a < 4; ++a)
                #pragma unroll
                for (int b = 0; b < 4; ++b) s[a][b] = 0.f;
            #pragma unroll 4
            for (int k = 0; k < 64; ++k) {
                float4 u = *(const float4*)&sS[k][r0];
                float4 v = *(const float4*)&X[k * NSS + c0];
                float uu[4] = {u.x, u.y, u.z, u.w};
                float vv[4] = {v.x, v.y, v.z, v.w};
                #pragma unroll
                for (int a = 0; a < 4; ++a)
                    #pragma unroll
                    for (int b = 0; b < 4; ++b) s[a][b] += uu[a] * vv[b];
            }
            #pragma unroll
            for (int a = 0; a < 4; ++a)
                *(float4*)&sT[r0 + a][c0] = (float4){s[a][0], s[a][1], s[a][2], s[a][3]};
        }
        __syncthreads();
        {
            float s[4][4];
            #pragma unroll
            for (int a = 0; a < 4; ++a)
                #pragma unroll
                for (int b = 0; b < 4; ++b) s[a][b] = 0.f;
            #pragma unroll 4
            for (int k = 0; k < 64; ++k) {
                float4 u = *(const float4*)&X[k * NSS + r0];
                float4 v = *(const float4*)&sT[k][c0];
                float uu[4] = {u.x, u.y, u.z, u.w};
                float vv[4] = {v.x, v.y, v.z, v.w};
                #pragma unroll
                for (int a = 0; a < 4; ++a)
                    #pragma unroll
                    for (int b = 0; b < 4; ++b) s[a][b] += uu[a] * vv[b];
            }
            #pragma unroll
            for (int a = 0; a < 4; ++a) {
                float4 xo = *(const float4*)&X[(r0 + a) * NSS + c0];
                float4 w;
                w.x = 2.f * xo.x - s[a][0];
                w.y = 2.f * xo.y - s[a][1];
                w.z = 2.f * xo.z - s[a][2];
                w.w = 2.f * xo.w - s[a][3];
                *(float4*)&Xn[(r0 + a) * NSS + c0] = w;
            }
        }
        __syncthreads();
        float* tmp = X; X = Xn; Xn = tmp;
    }
    for (int i = t; i < 4096; i += 256)
        M[i] = X[(i >> 6) * NSS + (i & 63)];
}

// Per (b,k): mean = z[b, idx, :] @ M ; write bias; zero accumulators + cnt.
__global__ __launch_bounds__(64) void k_init(const float* __restrict__ z,
                                             const int* __restrict__ idxs,
                                             const float* __restrict__ M,
                                             const float* __restrict__ IA,
                                             float* __restrict__ out_mean,
                                             float* __restrict__ bias,
                                             float* __restrict__ nk,
                                             float* __restrict__ macc,
                                             int* __restrict__ cnt) {
    int k = blockIdx.x, b = blockIdx.y;
    int l = threadIdx.x;
    int bk = b * KK + k;
    __shared__ float srow[64];
    __shared__ float smean[64];
    int idx = idxs[bk];
    srow[l] = z[((size_t)b * NN + idx) * LL + l];
    __syncthreads();
    float nm = 0.f;
    #pragma unroll 8
    for (int m = 0; m < 64; ++m) nm += srow[m] * M[m * 64 + l];
    out_mean[(size_t)bk * LL + l] = nm;
    smean[l] = nm;
    __syncthreads();
    float cm = 0.f;
    #pragma unroll 8
    for (int m = 0; m < 64; ++m) cm += smean[m] * IA[m * 64 + l];
    float sqm = nm * nm;
    float sqc = cm * cm;
    for (int off = 32; off > 0; off >>= 1) {
        sqm += __shfl_down(sqm, off);
        sqc += __shfl_down(sqc, off);
    }
    if (l == 0) {
        bias[bk] = logf(1.0f / KK) - 0.5f * (sqm + sqc);
        nk[bk] = 0.f;
        if (k == 0) cnt[b] = 0;
    }
    macc[(size_t)bk * LL + l] = 0.f;
}

// Fused EM pass (r10 structure, grid reshaped for 4 blocks/CU):
//  - 512 threads (8 waves); wave q owns zrows [16q,16q+16).
//  - thread (q,lg4,ln) stages row 16q+ln, cols {8lg4..+8, 32+8lg4..+8} into
//    REGISTERS (its phase-A MFMA B-fragments directly; no z LDS for A).
//  - phase B: wave q -> col-tile (q&3), row-chunks {2(q>>2), 2(q>>2)+1}.
//  - 2 barriers/tile; next tile's global loads issued at tile top.
//  - All LDS reads are consumed by register ops before their barrier, so no
//    pending-read race (the r11 hazard class needs a queued read crossing a
//    barrier into an overwrite window).
__global__ __launch_bounds__(512, 8) void k_empass(const float* __restrict__ z,
                                                   float* __restrict__ mean,
                                                   float* __restrict__ bias,
                                                   float* __restrict__ nk,
                                                   float* __restrict__ macc,
                                                   int* __restrict__ cnt,
                                                   const float* __restrict__ M,
                                                   const float* __restrict__ IA,
                                                   float* __restrict__ out_pi,
                                                   float* __restrict__ out_trace) {
    __shared__ __align__(16) unsigned short mhl[2][32][ZSB];   // mean hi/lo, rows 20-31 zero
    __shared__ __align__(16) unsigned short zT[64][ZTS];       // z hi, [col][row]
    __shared__ __align__(16) unsigned short ptT[32][PTTS];     // posteriors [comp][zrow]
    __shared__ __align__(16) float bias_s[32];                 // comps >=20: -1e30
    __shared__ float nkred[8][KK];
    __shared__ int isLast;
    int t = threadIdx.x;
    int lane = t & 63;
    int q = t >> 6;             // wave id 0..7, owns zrows [16q,16q+16)
    int ln = lane & 15;
    int lg4 = lane >> 4;        // 0..3
    int b = blockIdx.y;
    size_t zbase = ((size_t)b * NN + (size_t)blockIdx.x * (TILE * NT)) * LL;
    int zr = q * 16 + ln;       // this thread's z row (tile-local)
    int fbase = zr * 16 + 2 * lg4;  // float4 index of first staged segment

    // ---- stage mean (hi/lo split) + zero pad rows + bias ----
    for (int i = t; i < KK * LL; i += 512) {
        float f = mean[(size_t)b * KK * LL + i];
        int k = i >> 6, c = i & 63;
        unsigned short h = f2bf(f);
        mhl[0][k][c] = h;
        mhl[1][k][c] = f2bf(f - bf2f(h));
    }
    for (int i = 20 * ZSB + t; i < 32 * ZSB; i += 512) {
        (&mhl[0][0][0])[i] = 0;
        (&mhl[1][0][0])[i] = 0;
    }
    if (t < 32) bias_s[t] = (t < KK) ? bias[b * KK + t] : -1e30f;

    const float4* zg = (const float4*)(z + zbase);
    float4 pf[4];
    // prologue: issue tile-0 loads (latency hides under mean staging)
    pf[0] = zg[fbase];
    pf[1] = zg[fbase + 1];
    pf[2] = zg[fbase + 8];
    pf[3] = zg[fbase + 9];
    __syncthreads();
    float4 b0 = *(const float4*)&bias_s[lg4 * 4];
    float4 b1 = *(const float4*)&bias_s[16 + lg4 * 4];
    // hoist mean fragments: [ks*4 + {mh0,ml0,mh1,ml1}]
    s16x8 mf[8];
    #pragma unroll
    for (int ks = 0; ks < 2; ++ks) {
        int kc = ks * 32 + lg4 * 8;
        mf[ks * 4 + 0] = *(const s16x8*)&mhl[0][ln][kc];
        mf[ks * 4 + 1] = *(const s16x8*)&mhl[1][ln][kc];
        mf[ks * 4 + 2] = *(const s16x8*)&mhl[0][16 + ln][kc];
        mf[ks * 4 + 3] = *(const s16x8*)&mhl[1][16 + ln][kc];
    }

    int ct = q & 3;                 // phase-B col-tile
    int chb = 2 * (q >> 2);         // phase-B row-chunk base (0 or 2)
    f32x4 bacc0 = {0.f, 0.f, 0.f, 0.f};
    f32x4 bacc1 = {0.f, 0.f, 0.f, 0.f};
    float nkp0[4] = {0.f, 0.f, 0.f, 0.f};
    float nkp1[4] = {0.f, 0.f, 0.f, 0.f};

    for (int tt = 0; tt < NT; ++tt) {
        // ---- convert staged regs -> bf16 hi/lo fragments (phase-A B-operand) ----
        s16x8 zh0, zl0, zh1, zl1;
        #pragma unroll
        for (int i = 0; i < 2; ++i) {
            float4 v = pf[i];
            float vv[4] = {v.x, v.y, v.z, v.w};
            #pragma unroll
            for (int j = 0; j < 4; ++j) {
                unsigned short h = f2bf(vv[j]);
                zh0[4 * i + j] = (short)h;
                zl0[4 * i + j] = (short)f2bf(vv[j] - bf2f(h));
            }
        }
        #pragma unroll
        for (int i = 0; i < 2; ++i) {
            float4 v = pf[2 + i];
            float vv[4] = {v.x, v.y, v.z, v.w};
            #pragma unroll
            for (int j = 0; j < 4; ++j) {
                unsigned short h = f2bf(vv[j]);
                zh1[4 * i + j] = (short)h;
                zl1[4 * i + j] = (short)f2bf(vv[j] - bf2f(h));
            }
        }
        // ---- issue next tile's loads (consumed after bar2) ----
        if (tt + 1 < NT) {
            size_t o = (size_t)(tt + 1) * 2048;
            pf[0] = zg[o + fbase];
            pf[1] = zg[o + fbase + 1];
            pf[2] = zg[o + fbase + 8];
            pf[3] = zg[o + fbase + 9];
        }
        // ---- write zT for current tile (window: after bar2(t-1), before bar1) ----
        #pragma unroll
        for (int e = 0; e < 8; ++e) {
            zT[8 * lg4 + e][zr]      = (unsigned short)zh0[e];
            zT[32 + 8 * lg4 + e][zr] = (unsigned short)zh1[e];
        }

        // ---- phase A: D[comp][zrow] = mean·zᵀ (3-product bf16 split) ----
        f32x4 acc0 = (f32x4){b0.x, b0.y, b0.z, b0.w};
        f32x4 acc1 = (f32x4){b1.x, b1.y, b1.z, b1.w};
        acc0 = MFMA_BF16(mf[0], zh0, acc0, 0, 0, 0);
        acc0 = MFMA_BF16(mf[1], zh0, acc0, 0, 0, 0);
        acc0 = MFMA_BF16(mf[0], zl0, acc0, 0, 0, 0);
        acc0 = MFMA_BF16(mf[4], zh1, acc0, 0, 0, 0);
        acc0 = MFMA_BF16(mf[5], zh1, acc0, 0, 0, 0);
        acc0 = MFMA_BF16(mf[4], zl1, acc0, 0, 0, 0);
        acc1 = MFMA_BF16(mf[2], zh0, acc1, 0, 0, 0);
        acc1 = MFMA_BF16(mf[3], zh0, acc1, 0, 0, 0);
        acc1 = MFMA_BF16(mf[2], zl0, acc1, 0, 0, 0);
        acc1 = MFMA_BF16(mf[6], zh1, acc1, 0, 0, 0);
        acc1 = MFMA_BF16(mf[7], zh1, acc1, 0, 0, 0);
        acc1 = MFMA_BF16(mf[6], zl1, acc1, 0, 0, 0);

        // ---- softmax over comps (regs + 2+2 shfls), branchless ----
        {
            float m = fmaxf(fmaxf(fmaxf(acc0[0], acc0[1]), fmaxf(acc0[2], acc0[3])),
                            fmaxf(fmaxf(acc1[0], acc1[1]), fmaxf(acc1[2], acc1[3])));
            m = fmaxf(m, __shfl_xor(m, 16));
            m = fmaxf(m, __shfl_xor(m, 32));
            float e0[4], e1[4];
            float sm = 0.f;
            #pragma unroll
            for (int j = 0; j < 4; ++j) {
                e0[j] = __expf(acc0[j] - m); sm += e0[j];
                e1[j] = __expf(acc1[j] - m); sm += e1[j];
            }
            sm += __shfl_xor(sm, 16);
            sm += __shfl_xor(sm, 32);
            float inv = 1.0f / sm;
            #pragma unroll
            for (int j = 0; j < 4; ++j) {
                float p0 = e0[j] * inv;
                float p1 = e1[j] * inv;
                nkp0[j] += p0;
                nkp1[j] += p1;
                ptT[lg4 * 4 + j][zr] = f2bf(p0);
                ptT[16 + lg4 * 4 + j][zr] = f2bf(p1);
            }
        }
        __syncthreads();    // bar1: ptT + zT complete

        // ---- phase B: D[comp][col] partial; wave q -> cols ct*16..+16 ----
        #pragma unroll
        for (int chi = 0; chi < 2; ++chi) {
            int rr = (chb + chi) * 32 + lg4 * 8;
            s16x8 zb  = *(const s16x8*)&zT[ct * 16 + ln][rr];
            s16x8 af0 = *(const s16x8*)&ptT[ln][rr];
            s16x8 af1 = *(const s16x8*)&ptT[16 + ln][rr];
            bacc0 = MFMA_BF16(af0, zb, bacc0, 0, 0, 0);
            bacc1 = MFMA_BF16(af1, zb, bacc1, 0, 0, 0);
        }
        __syncthreads();    // bar2: all B-reads done (consumed by MFMA pre-barrier)
    }

    // ---- Nk reduce: sum over ln lanes ----
    #pragma unroll
    for (int j = 0; j < 4; ++j) {
        nkp0[j] += __shfl_xor(nkp0[j], 1);
        nkp0[j] += __shfl_xor(nkp0[j], 2);
        nkp0[j] += __shfl_xor(nkp0[j], 4);
        nkp0[j] += __shfl_xor(nkp0[j], 8);
        nkp1[j] += __shfl_xor(nkp1[j], 1);
        nkp1[j] += __shfl_xor(nkp1[j], 2);
        nkp1[j] += __shfl_xor(nkp1[j], 4);
        nkp1[j] += __shfl_xor(nkp1[j], 8);
    }
    if (ln == 0) {
        #pragma unroll
        for (int j = 0; j < 4; ++j) nkred[q][lg4 * 4 + j] = nkp0[j];
        if (lg4 == 0) {
            #pragma unroll
            for (int j = 0; j < 4; ++j) nkred[q][16 + j] = nkp1[j];
        }
    }

    // ---- macc atomics: comp = 4lg4+reg (and 16+reg), col = 16ct+ln ----
    int col = ct * 16 + ln;
    #pragma unroll
    for (int reg = 0; reg < 4; ++reg) {
        int comp = lg4 * 4 + reg;
        atomicAdd(&macc[((size_t)b * KK + comp) * LL + col], bacc0[reg]);
    }
    if (lg4 == 0) {
        #pragma unroll
        for (int reg = 0; reg < 4; ++reg)
            atomicAdd(&macc[((size_t)b * KK + 16 + reg) * LL + col], bacc1[reg]);
    }
    __syncthreads();
    if (t < KK) {
        float sum = 0.f;
        #pragma unroll
        for (int w = 0; w < 8; ++w) sum += nkred[w][t];
        atomicAdd(&nk[b * KK + t], sum);
    }
    __syncthreads();            // all this block's atomics retired
    if (t == 0) {
        __threadfence();
        int old = atomicAdd(&cnt[b], 1);
        isLast = (old == CHUNKS - 1) ? 1 : 0;
    }
    __syncthreads();
    if (!isLast) return;

    // ---- finalize batch b (last block; waves 0-3 cover 20 comps) ----
    if (q < 4) {
        float* fs = (float*)&zT[0][0];
        float* sraw = fs + q * 160;
        float* smean = sraw + 64;
        int l = lane;
        #pragma unroll
        for (int kc5 = 0; kc5 < 5; ++kc5) {
            int comp = kc5 * 4 + q;
            int bk = b * KK + comp;
            size_t mb = (size_t)bk * LL;
            float nkv = 0.f;
            if (l == 0) nkv = atomicExch(&nk[bk], 0.f);
            nkv = __shfl(nkv, 0);
            float nkc = fmaxf(nkv, 1e-22f);
            float raw = atomicExch(&macc[mb + l], 0.f) / nkc;
            sraw[l] = raw;
            float nm = 0.f;
            #pragma unroll 8
            for (int m = 0; m < 64; ++m) nm += sraw[m] * M[m * 64 + l];
            mean[mb + l] = nm;
            smean[l] = nm;
            float cm = 0.f;
            #pragma unroll 8
            for (int m = 0; m < 64; ++m) cm += smean[m] * IA[m * 64 + l];
            float sqm = nm * nm;
            float sqc = cm * cm;
            #pragma unroll
            for (int off = 32; off > 0; off >>= 1) {
                sqm += __shfl_down(sqm, off);
                sqc += __shfl_down(sqc, off);
            }
            if (l == 0) {
                float pi = nkc * (1.0f / NN);
                bias[bk] = logf(pi) - 0.5f * (sqm + sqc);
                out_pi[bk] = pi;
                out_trace[bk] = 1.0f;
            }
        }
    }
    if (t == 0) cnt[b] = 0;
}

extern "C" void kernel_launch(void* const* d_in, const int* in_sizes, int n_in,
                              void* d_out, int out_size, void* d_ws, size_t ws_size,
                              hipStream_t stream) {
    const float* z = (const float*)d_in[0];
    const float* A = (const float*)d_in[1];
    const int* idxs = (const int*)d_in[2];

    float* out_pi = (float*)d_out;
    float* out_mean = out_pi + BB * KK;
    float* out_trace = out_mean + (size_t)BB * KK * LL;

    float* ws = (float*)d_ws;
    float* IA = ws;
    float* M = ws + 4096;
    float* bias = ws + 8192;
    float* nk = ws + 9472;
    float* macc = ws + 10752;
    int* cnt = (int*)(ws + 92672);

    k_setup<<<1, 256, 0, stream>>>(A, IA, M);
    k_init<<<dim3(KK, BB), 64, 0, stream>>>(z, idxs, M, IA, out_mean, bias, nk, macc, cnt);
    for (int it = 0; it < 5; ++it) {
        k_empass<<<dim3(CHUNKS, BB), 512, 0, stream>>>(z, out_mean, bias, nk, macc,
                                                       cnt, M, IA, out_pi, out_trace);
    }
}

// Round 14
// 428.160 us; speedup vs baseline: 2.2264x; 2.2264x over previous
//
#include <hip/hip_runtime.h>
#include <math.h>

#define BB 64
#define NN 8192
#define LL 64
#define KK 20
#define TILE 128
#define NT 4        // tiles per block
#define CHUNKS 16   // blocks per batch entry: CHUNKS*NT*TILE == NN (1024 blocks = 4/CU)
#define ZSB 72      // mhl row stride (ushorts)
#define ZTS 136     // zT row stride (ushorts): 272 B
#define PTTS 136    // ptT row stride (ushorts)
#define NSS 68      // Newton-Schulz matrix stride (floats)

typedef float f32x4 __attribute__((ext_vector_type(4)));
typedef short s16x8 __attribute__((ext_vector_type(8)));

#define MFMA_BF16 __builtin_amdgcn_mfma_f32_16x16x32_bf16

__device__ __forceinline__ unsigned short f2bf(float f) {   // RNE fp32->bf16
    unsigned int u = __float_as_uint(f);
    u += 0x7fffu + ((u >> 16) & 1u);
    return (unsigned short)(u >> 16);
}
__device__ __forceinline__ float bf2f(unsigned short h) {
    return __uint_as_float(((unsigned int)h) << 16);
}

// ---------------------------------------------------------------------------
// ws layout (floats): IA @0, M @4096, bias @8192, nk @9472, macc @10752,
// cnt(int) @92672. Requires ws_size >= 370,944 B.
// ---------------------------------------------------------------------------

// IA = I - A ; M = inv(S), S = I + IA·IAᵀ, Newton-Schulz (8 iters, SPD).
__global__ __launch_bounds__(256) void k_setup(const float* __restrict__ A,
                                               float* __restrict__ IA,
                                               float* __restrict__ M) {
    __shared__ __align__(16) float sS[64][NSS];
    __shared__ __align__(16) float sXa[64][NSS];
    __shared__ __align__(16) float sXb[64][NSS];
    __shared__ __align__(16) float sT[64][NSS];   // iaT during build, then T
    __shared__ float rowsum[64];
    __shared__ float alpha_s;
    int t = threadIdx.x;
    int r0 = (t >> 4) << 2;
    int c0 = (t & 15) << 2;

    for (int i = t; i < 4096; i += 256) {
        int r = i >> 6, c = i & 63;
        float v = (r == c ? 1.0f : 0.0f) - A[i];
        IA[i] = v;
        sT[c][r] = v;
    }
    __syncthreads();
    {
        float s[4][4];
        #pragma unroll
        for (int a = 0; a < 4; ++a)
            #pragma unroll
            for (int b = 0; b < 4; ++b) s[a][b] = 0.f;
        #pragma unroll 4
        for (int l = 0; l < 64; ++l) {
            float4 u = *(const float4*)&sT[l][r0];
            float4 v = *(const float4*)&sT[l][c0];
            float uu[4] = {u.x, u.y, u.z, u.w};
            float vv[4] = {v.x, v.y, v.z, v.w};
            #pragma unroll
            for (int a = 0; a < 4; ++a)
                #pragma unroll
                for (int b = 0; b < 4; ++b) s[a][b] += uu[a] * vv[b];
        }
        #pragma unroll
        for (int a = 0; a < 4; ++a) {
            int r = r0 + a;
            float4 w;
            w.x = s[a][0] + (r == c0 + 0 ? 1.f : 0.f);
            w.y = s[a][1] + (r == c0 + 1 ? 1.f : 0.f);
            w.z = s[a][2] + (r == c0 + 2 ? 1.f : 0.f);
            w.w = s[a][3] + (r == c0 + 3 ? 1.f : 0.f);
            *(float4*)&sS[r][c0] = w;
        }
    }
    __syncthreads();
    if (t < 64) {
        float sm = 0.f;
        #pragma unroll 4
        for (int c = 0; c < 64; c += 4) {
            float4 v = *(const float4*)&sS[t][c];
            sm += fabsf(v.x) + fabsf(v.y) + fabsf(v.z) + fabsf(v.w);
        }
        rowsum[t] = sm;
    }
    __syncthreads();
    if (t == 0) {
        float mx = rowsum[0];
        for (int i = 1; i < 64; ++i) mx = fmaxf(mx, rowsum[i]);
        alpha_s = 2.0f / (1.0f + mx);
    }
    __syncthreads();
    float alpha = alpha_s;
    for (int i = t; i < 4096; i += 256) {
        int r = i >> 6, c = i & 63;
        sXa[r][c] = (r == c) ? alpha : 0.f;
    }
    __syncthreads();

    float* X  = &sXa[0][0];
    float* Xn = &sXb[0][0];
    for (int it = 0; it < 8; ++it) {
        {
            float s[4][4];
            #pragma unroll
            for (int a = 0; a < 4; ++a)
                #pragma unroll
                for (int b = 0; b < 4; ++b) s[a][b] = 0.f;
            #pragma unroll 4
            for (int k = 0; k < 64; ++k) {
                float4 u = *(const float4*)&sS[k][r0];
                float4 v = *(const float4*)&X[k * NSS + c0];
                float uu[4] = {u.x, u.y, u.z, u.w};
                float vv[4] = {v.x, v.y, v.z, v.w};
                #pragma unroll
                for (int a = 0; a < 4; ++a)
                    #pragma unroll
                    for (int b = 0; b < 4; ++b) s[a][b] += uu[a] * vv[b];
            }
            #pragma unroll
            for (int a = 0; a < 4; ++a)
                *(float4*)&sT[r0 + a][c0] = (float4){s[a][0], s[a][1], s[a][2], s[a][3]};
        }
        __syncthreads();
        {
            float s[4][4];
            #pragma unroll
            for (int a = 0; a < 4; ++a)
                #pragma unroll
                for (int b = 0; b < 4; ++b) s[a][b] = 0.f;
            #pragma unroll 4
            for (int k = 0; k < 64; ++k) {
                float4 u = *(const float4*)&X[k * NSS + r0];
                float4 v = *(const float4*)&sT[k][c0];
                float uu[4] = {u.x, u.y, u.z, u.w};
                float vv[4] = {v.x, v.y, v.z, v.w};
                #pragma unroll
                for (int a = 0; a < 4; ++a)
                    #pragma unroll
                    for (int b = 0; b < 4; ++b) s[a][b] += uu[a] * vv[b];
            }
            #pragma unroll
            for (int a = 0; a < 4; ++a) {
                float4 xo = *(const float4*)&X[(r0 + a) * NSS + c0];
                float4 w;
                w.x = 2.f * xo.x - s[a][0];
                w.y = 2.f * xo.y - s[a][1];
                w.z = 2.f * xo.z - s[a][2];
                w.w = 2.f * xo.w - s[a][3];
                *(float4*)&Xn[(r0 + a) * NSS + c0] = w;
            }
        }
        __syncthreads();
        float* tmp = X; X = Xn; Xn = tmp;
    }
    for (int i = t; i < 4096; i += 256)
        M[i] = X[(i >> 6) * NSS + (i & 63)];
}

// Per (b,k): mean = z[b, idx, :] @ M ; write bias; zero accumulators + cnt.
__global__ __launch_bounds__(64) void k_init(const float* __restrict__ z,
                                             const int* __restrict__ idxs,
                                             const float* __restrict__ M,
                                             const float* __restrict__ IA,
                                             float* __restrict__ out_mean,
                                             float* __restrict__ bias,
                                             float* __restrict__ nk,
                                             float* __restrict__ macc,
                                             int* __restrict__ cnt) {
    int k = blockIdx.x, b = blockIdx.y;
    int l = threadIdx.x;
    int bk = b * KK + k;
    __shared__ float srow[64];
    __shared__ float smean[64];
    int idx = idxs[bk];
    srow[l] = z[((size_t)b * NN + idx) * LL + l];
    __syncthreads();
    float nm = 0.f;
    #pragma unroll 8
    for (int m = 0; m < 64; ++m) nm += srow[m] * M[m * 64 + l];
    out_mean[(size_t)bk * LL + l] = nm;
    smean[l] = nm;
    __syncthreads();
    float cm = 0.f;
    #pragma unroll 8
    for (int m = 0; m < 64; ++m) cm += smean[m] * IA[m * 64 + l];
    float sqm = nm * nm;
    float sqc = cm * cm;
    for (int off = 32; off > 0; off >>= 1) {
        sqm += __shfl_down(sqm, off);
        sqc += __shfl_down(sqc, off);
    }
    if (l == 0) {
        bias[bk] = logf(1.0f / KK) - 0.5f * (sqm + sqc);
        nk[bk] = 0.f;
        if (k == 0) cnt[b] = 0;
    }
    macc[(size_t)bk * LL + l] = 0.f;
}

// Fused EM pass (r10 structure, 1024-block grid, natural VGPR allocation):
//  - 512 threads (8 waves); wave q owns zrows [16q,16q+16).
//  - register-direct phase-A staging (no z LDS for A); LDS 36 KB.
//  - launch_bounds(512,4): allocator targets 128 VGPRs but natural use is
//    ~60 <= 64, so HW still reaches 8 waves/EU = 4 blocks/CU with the
//    1024-block grid. (512,8) pinned regs to 32 and spilled 226 MB — never
//    tighten the bound below the natural allocation.
__global__ __launch_bounds__(512, 4) void k_empass(const float* __restrict__ z,
                                                   float* __restrict__ mean,
                                                   float* __restrict__ bias,
                                                   float* __restrict__ nk,
                                                   float* __restrict__ macc,
                                                   int* __restrict__ cnt,
                                                   const float* __restrict__ M,
                                                   const float* __restrict__ IA,
                                                   float* __restrict__ out_pi,
                                                   float* __restrict__ out_trace) {
    __shared__ __align__(16) unsigned short mhl[2][32][ZSB];   // mean hi/lo, rows 20-31 zero
    __shared__ __align__(16) unsigned short zT[64][ZTS];       // z hi, [col][row]
    __shared__ __align__(16) unsigned short ptT[32][PTTS];     // posteriors [comp][zrow]
    __shared__ __align__(16) float bias_s[32];                 // comps >=20: -1e30
    __shared__ float nkred[8][KK];
    __shared__ int isLast;
    int t = threadIdx.x;
    int lane = t & 63;
    int q = t >> 6;             // wave id 0..7, owns zrows [16q,16q+16)
    int ln = lane & 15;
    int lg4 = lane >> 4;        // 0..3
    int b = blockIdx.y;
    size_t zbase = ((size_t)b * NN + (size_t)blockIdx.x * (TILE * NT)) * LL;
    int zr = q * 16 + ln;       // this thread's z row (tile-local)
    int fbase = zr * 16 + 2 * lg4;  // float4 index of first staged segment

    // ---- stage mean (hi/lo split) + zero pad rows + bias ----
    for (int i = t; i < KK * LL; i += 512) {
        float f = mean[(size_t)b * KK * LL + i];
        int k = i >> 6, c = i & 63;
        unsigned short h = f2bf(f);
        mhl[0][k][c] = h;
        mhl[1][k][c] = f2bf(f - bf2f(h));
    }
    for (int i = 20 * ZSB + t; i < 32 * ZSB; i += 512) {
        (&mhl[0][0][0])[i] = 0;
        (&mhl[1][0][0])[i] = 0;
    }
    if (t < 32) bias_s[t] = (t < KK) ? bias[b * KK + t] : -1e30f;

    const float4* zg = (const float4*)(z + zbase);
    float4 pf[4];
    // prologue: issue tile-0 loads (latency hides under mean staging)
    pf[0] = zg[fbase];
    pf[1] = zg[fbase + 1];
    pf[2] = zg[fbase + 8];
    pf[3] = zg[fbase + 9];
    __syncthreads();
    float4 b0 = *(const float4*)&bias_s[lg4 * 4];
    float4 b1 = *(const float4*)&bias_s[16 + lg4 * 4];
    // hoist mean fragments: [ks*4 + {mh0,ml0,mh1,ml1}]
    s16x8 mf[8];
    #pragma unroll
    for (int ks = 0; ks < 2; ++ks) {
        int kc = ks * 32 + lg4 * 8;
        mf[ks * 4 + 0] = *(const s16x8*)&mhl[0][ln][kc];
        mf[ks * 4 + 1] = *(const s16x8*)&mhl[1][ln][kc];
        mf[ks * 4 + 2] = *(const s16x8*)&mhl[0][16 + ln][kc];
        mf[ks * 4 + 3] = *(const s16x8*)&mhl[1][16 + ln][kc];
    }

    int ct = q & 3;                 // phase-B col-tile
    int chb = 2 * (q >> 2);         // phase-B row-chunk base (0 or 2)
    f32x4 bacc0 = {0.f, 0.f, 0.f, 0.f};
    f32x4 bacc1 = {0.f, 0.f, 0.f, 0.f};
    float nkp0[4] = {0.f, 0.f, 0.f, 0.f};
    float nkp1[4] = {0.f, 0.f, 0.f, 0.f};

    for (int tt = 0; tt < NT; ++tt) {
        // ---- convert staged regs -> bf16 hi/lo fragments (phase-A B-operand) ----
        s16x8 zh0, zl0, zh1, zl1;
        #pragma unroll
        for (int i = 0; i < 2; ++i) {
            float4 v = pf[i];
            float vv[4] = {v.x, v.y, v.z, v.w};
            #pragma unroll
            for (int j = 0; j < 4; ++j) {
                unsigned short h = f2bf(vv[j]);
                zh0[4 * i + j] = (short)h;
                zl0[4 * i + j] = (short)f2bf(vv[j] - bf2f(h));
            }
        }
        #pragma unroll
        for (int i = 0; i < 2; ++i) {
            float4 v = pf[2 + i];
            float vv[4] = {v.x, v.y, v.z, v.w};
            #pragma unroll
            for (int j = 0; j < 4; ++j) {
                unsigned short h = f2bf(vv[j]);
                zh1[4 * i + j] = (short)h;
                zl1[4 * i + j] = (short)f2bf(vv[j] - bf2f(h));
            }
        }
        // ---- issue next tile's loads (consumed after bar2) ----
        if (tt + 1 < NT) {
            size_t o = (size_t)(tt + 1) * 2048;
            pf[0] = zg[o + fbase];
            pf[1] = zg[o + fbase + 1];
            pf[2] = zg[o + fbase + 8];
            pf[3] = zg[o + fbase + 9];
        }
        // ---- write zT for current tile (window: after bar2(t-1), before bar1) ----
        #pragma unroll
        for (int e = 0; e < 8; ++e) {
            zT[8 * lg4 + e][zr]      = (unsigned short)zh0[e];
            zT[32 + 8 * lg4 + e][zr] = (unsigned short)zh1[e];
        }

        // ---- phase A: D[comp][zrow] = mean·zᵀ (3-product bf16 split) ----
        f32x4 acc0 = (f32x4){b0.x, b0.y, b0.z, b0.w};
        f32x4 acc1 = (f32x4){b1.x, b1.y, b1.z, b1.w};
        acc0 = MFMA_BF16(mf[0], zh0, acc0, 0, 0, 0);
        acc0 = MFMA_BF16(mf[1], zh0, acc0, 0, 0, 0);
        acc0 = MFMA_BF16(mf[0], zl0, acc0, 0, 0, 0);
        acc0 = MFMA_BF16(mf[4], zh1, acc0, 0, 0, 0);
        acc0 = MFMA_BF16(mf[5], zh1, acc0, 0, 0, 0);
        acc0 = MFMA_BF16(mf[4], zl1, acc0, 0, 0, 0);
        acc1 = MFMA_BF16(mf[2], zh0, acc1, 0, 0, 0);
        acc1 = MFMA_BF16(mf[3], zh0, acc1, 0, 0, 0);
        acc1 = MFMA_BF16(mf[2], zl0, acc1, 0, 0, 0);
        acc1 = MFMA_BF16(mf[6], zh1, acc1, 0, 0, 0);
        acc1 = MFMA_BF16(mf[7], zh1, acc1, 0, 0, 0);
        acc1 = MFMA_BF16(mf[6], zl1, acc1, 0, 0, 0);

        // ---- softmax over comps (regs + 2+2 shfls), branchless ----
        {
            float m = fmaxf(fmaxf(fmaxf(acc0[0], acc0[1]), fmaxf(acc0[2], acc0[3])),
                            fmaxf(fmaxf(acc1[0], acc1[1]), fmaxf(acc1[2], acc1[3])));
            m = fmaxf(m, __shfl_xor(m, 16));
            m = fmaxf(m, __shfl_xor(m, 32));
            float e0[4], e1[4];
            float sm = 0.f;
            #pragma unroll
            for (int j = 0; j < 4; ++j) {
                e0[j] = __expf(acc0[j] - m); sm += e0[j];
                e1[j] = __expf(acc1[j] - m); sm += e1[j];
            }
            sm += __shfl_xor(sm, 16);
            sm += __shfl_xor(sm, 32);
            float inv = 1.0f / sm;
            #pragma unroll
            for (int j = 0; j < 4; ++j) {
                float p0 = e0[j] * inv;
                float p1 = e1[j] * inv;
                nkp0[j] += p0;
                nkp1[j] += p1;
                ptT[lg4 * 4 + j][zr] = f2bf(p0);
                ptT[16 + lg4 * 4 + j][zr] = f2bf(p1);
            }
        }
        __syncthreads();    // bar1: ptT + zT complete

        // ---- phase B: D[comp][col] partial; wave q -> cols ct*16..+16 ----
        #pragma unroll
        for (int chi = 0; chi < 2; ++chi) {
            int rr = (chb + chi) * 32 + lg4 * 8;
            s16x8 zb  = *(const s16x8*)&zT[ct * 16 + ln][rr];
            s16x8 af0 = *(const s16x8*)&ptT[ln][rr];
            s16x8 af1 = *(const s16x8*)&ptT[16 + ln][rr];
            bacc0 = MFMA_BF16(af0, zb, bacc0, 0, 0, 0);
            bacc1 = MFMA_BF16(af1, zb, bacc1, 0, 0, 0);
        }
        __syncthreads();    // bar2: all B-reads done (consumed by MFMA pre-barrier)
    }

    // ---- Nk reduce: sum over ln lanes ----
    #pragma unroll
    for (int j = 0; j < 4; ++j) {
        nkp0[j] += __shfl_xor(nkp0[j], 1);
        nkp0[j] += __shfl_xor(nkp0[j], 2);
        nkp0[j] += __shfl_xor(nkp0[j], 4);
        nkp0[j] += __shfl_xor(nkp0[j], 8);
        nkp1[j] += __shfl_xor(nkp1[j], 1);
        nkp1[j] += __shfl_xor(nkp1[j], 2);
        nkp1[j] += __shfl_xor(nkp1[j], 4);
        nkp1[j] += __shfl_xor(nkp1[j], 8);
    }
    if (ln == 0) {
        #pragma unroll
        for (int j = 0; j < 4; ++j) nkred[q][lg4 * 4 + j] = nkp0[j];
        if (lg4 == 0) {
            #pragma unroll
            for (int j = 0; j < 4; ++j) nkred[q][16 + j] = nkp1[j];
        }
    }

    // ---- macc atomics: comp = 4lg4+reg (and 16+reg), col = 16ct+ln ----
    int col = ct * 16 + ln;
    #pragma unroll
    for (int reg = 0; reg < 4; ++reg) {
        int comp = lg4 * 4 + reg;
        atomicAdd(&macc[((size_t)b * KK + comp) * LL + col], bacc0[reg]);
    }
    if (lg4 == 0) {
        #pragma unroll
        for (int reg = 0; reg < 4; ++reg)
            atomicAdd(&macc[((size_t)b * KK + 16 + reg) * LL + col], bacc1[reg]);
    }
    __syncthreads();
    if (t < KK) {
        float sum = 0.f;
        #pragma unroll
        for (int w = 0; w < 8; ++w) sum += nkred[w][t];
        atomicAdd(&nk[b * KK + t], sum);
    }
    __syncthreads();            // all this block's atomics retired
    if (t == 0) {
        __threadfence();
        int old = atomicAdd(&cnt[b], 1);
        isLast = (old == CHUNKS - 1) ? 1 : 0;
    }
    __syncthreads();
    if (!isLast) return;

    // ---- finalize batch b (last block; waves 0-3 cover 20 comps) ----
    if (q < 4) {
        float* fs = (float*)&zT[0][0];
        float* sraw = fs + q * 160;
        float* smean = sraw + 64;
        int l = lane;
        #pragma unroll
        for (int kc5 = 0; kc5 < 5; ++kc5) {
            int comp = kc5 * 4 + q;
            int bk = b * KK + comp;
            size_t mb = (size_t)bk * LL;
            float nkv = 0.f;
            if (l == 0) nkv = atomicExch(&nk[bk], 0.f);
            nkv = __shfl(nkv, 0);
            float nkc = fmaxf(nkv, 1e-22f);
            float raw = atomicExch(&macc[mb + l], 0.f) / nkc;
            sraw[l] = raw;
            float nm = 0.f;
            #pragma unroll 8
            for (int m = 0; m < 64; ++m) nm += sraw[m] * M[m * 64 + l];
            mean[mb + l] = nm;
            smean[l] = nm;
            float cm = 0.f;
            #pragma unroll 8
            for (int m = 0; m < 64; ++m) cm += smean[m] * IA[m * 64 + l];
            float sqm = nm * nm;
            float sqc = cm * cm;
            #pragma unroll
            for (int off = 32; off > 0; off >>= 1) {
                sqm += __shfl_down(sqm, off);
                sqc += __shfl_down(sqc, off);
            }
            if (l == 0) {
                float pi = nkc * (1.0f / NN);
                bias[bk] = logf(pi) - 0.5f * (sqm + sqc);
                out_pi[bk] = pi;
                out_trace[bk] = 1.0f;
            }
        }
    }
    if (t == 0) cnt[b] = 0;
}

extern "C" void kernel_launch(void* const* d_in, const int* in_sizes, int n_in,
                              void* d_out, int out_size, void* d_ws, size_t ws_size,
                              hipStream_t stream) {
    const float* z = (const float*)d_in[0];
    const float* A = (const float*)d_in[1];
    const int* idxs = (const int*)d_in[2];

    float* out_pi = (float*)d_out;
    float* out_mean = out_pi + BB * KK;
    float* out_trace = out_mean + (size_t)BB * KK * LL;

    float* ws = (float*)d_ws;
    float* IA = ws;
    float* M = ws + 4096;
    float* bias = ws + 8192;
    float* nk = ws + 9472;
    float* macc = ws + 10752;
    int* cnt = (int*)(ws + 92672);

    k_setup<<<1, 256, 0, stream>>>(A, IA, M);
    k_init<<<dim3(KK, BB), 64, 0, stream>>>(z, idxs, M, IA, out_mean, bias, nk, macc, cnt);
    for (int it = 0; it < 5; ++it) {
        k_empass<<<dim3(CHUNKS, BB), 512, 0, stream>>>(z, out_mean, bias, nk, macc,
                                                       cnt, M, IA, out_pi, out_trace);
    }
}

// Round 15
// 311.329 us; speedup vs baseline: 3.0619x; 1.3753x over previous
//
#include <hip/hip_runtime.h>
#include <math.h>

#define BB 64
#define NN 8192
#define LL 64
#define KK 20
#define TILE 128
#define NT 8        // tiles per block
#define CHUNKS 8    // blocks per batch entry: CHUNKS*NT*TILE == NN (512 blocks — r10 proven)
#define ZSB 72      // mhl row stride (ushorts)
#define ZTS 136     // zT row stride (ushorts): 272 B
#define PTTS 136    // ptT row stride (ushorts)
#define NSS 68      // Newton-Schulz matrix stride (floats)
#define NS_ITERS 5  // quadratic: e0~0.6 -> e5 = e0^32 ~ 5e-8 <= fp32 eps

typedef float f32x4 __attribute__((ext_vector_type(4)));
typedef short s16x8 __attribute__((ext_vector_type(8)));

#define MFMA_BF16 __builtin_amdgcn_mfma_f32_16x16x32_bf16

__device__ __forceinline__ unsigned short f2bf(float f) {   // RNE fp32->bf16
    unsigned int u = __float_as_uint(f);
    u += 0x7fffu + ((u >> 16) & 1u);
    return (unsigned short)(u >> 16);
}
__device__ __forceinline__ float bf2f(unsigned short h) {
    return __uint_as_float(((unsigned int)h) << 16);
}

// ---------------------------------------------------------------------------
// ws layout (floats): IA @0, M @4096, bias @8192, nk @9472, macc @10752,
// cnt(int) @92672. Requires ws_size >= 370,944 B.
// ---------------------------------------------------------------------------

// IA = I - A ; M = inv(S), S = I + IA·IAᵀ, Newton-Schulz.
// 1024 threads (16 waves = 4/SIMD: 4x the latency hiding of the old 4-wave
// version), thread owns a 2x2 block (float2 reads: u broadcast, v spread).
// 11 matmul-passes total (1 S-build + 2x5 NS) vs old 17.
__global__ __launch_bounds__(1024) void k_setup(const float* __restrict__ A,
                                                float* __restrict__ IA,
                                                float* __restrict__ M) {
    __shared__ __align__(16) float sS[64][NSS];
    __shared__ __align__(16) float sXa[64][NSS];
    __shared__ __align__(16) float sXb[64][NSS];
    __shared__ __align__(16) float sT[64][NSS];   // iaT during build, then T
    __shared__ float rowsum[64];
    __shared__ float alpha_s;
    int t = threadIdx.x;
    int r0 = (t >> 5) << 1;     // 0,2,...,62
    int c0 = (t & 31) << 1;     // 0,2,...,62

    for (int i = t; i < 4096; i += 1024) {
        int r = i >> 6, c = i & 63;
        float v = (r == c ? 1.0f : 0.0f) - A[i];
        IA[i] = v;
        sT[c][r] = v;           // iaT
    }
    __syncthreads();
    {   // S = I + IA·IAᵀ : S[r][c] = δ + Σ_l iaT[l][r]·iaT[l][c]
        float s00 = 0.f, s01 = 0.f, s10 = 0.f, s11 = 0.f;
        #pragma unroll 8
        for (int l = 0; l < 64; ++l) {
            float2 u = *(const float2*)&sT[l][r0];
            float2 v = *(const float2*)&sT[l][c0];
            s00 += u.x * v.x; s01 += u.x * v.y;
            s10 += u.y * v.x; s11 += u.y * v.y;
        }
        float2 w0, w1;
        w0.x = s00 + (r0 == c0     ? 1.f : 0.f);
        w0.y = s01 + (r0 == c0 + 1 ? 1.f : 0.f);
        w1.x = s10 + (r0 + 1 == c0     ? 1.f : 0.f);
        w1.y = s11 + (r0 + 1 == c0 + 1 ? 1.f : 0.f);
        *(float2*)&sS[r0][c0] = w0;
        *(float2*)&sS[r0 + 1][c0] = w1;
    }
    __syncthreads();
    if (t < 64) {               // ||S||_inf
        float sm = 0.f;
        #pragma unroll 4
        for (int c = 0; c < 64; c += 4) {
            float4 v = *(const float4*)&sS[t][c];
            sm += fabsf(v.x) + fabsf(v.y) + fabsf(v.z) + fabsf(v.w);
        }
        rowsum[t] = sm;
    }
    __syncthreads();
    if (t == 0) {
        float mx = rowsum[0];
        for (int i = 1; i < 64; ++i) mx = fmaxf(mx, rowsum[i]);
        alpha_s = 2.0f / (1.0f + mx);
    }
    __syncthreads();
    float alpha = alpha_s;
    for (int i = t; i < 4096; i += 1024) {
        int r = i >> 6, c = i & 63;
        sXa[r][c] = (r == c) ? alpha : 0.f;
    }
    __syncthreads();

    float* X  = &sXa[0][0];
    float* Xn = &sXb[0][0];
    for (int it = 0; it < NS_ITERS; ++it) {
        // T = S·X  (S, X symmetric -> T[r][c] = Σ_k S[k][r]·X[k][c])
        {
            float s00 = 0.f, s01 = 0.f, s10 = 0.f, s11 = 0.f;
            #pragma unroll 8
            for (int k = 0; k < 64; ++k) {
                float2 u = *(const float2*)&sS[k][r0];
                float2 v = *(const float2*)&X[k * NSS + c0];
                s00 += u.x * v.x; s01 += u.x * v.y;
                s10 += u.y * v.x; s11 += u.y * v.y;
            }
            *(float2*)&sT[r0][c0]     = (float2){s00, s01};
            *(float2*)&sT[r0 + 1][c0] = (float2){s10, s11};
        }
        __syncthreads();
        // Xn = 2X − X·T  (X sym -> (X·T)[r][c] = Σ_k X[k][r]·T[k][c])
        {
            float s00 = 0.f, s01 = 0.f, s10 = 0.f, s11 = 0.f;
            #pragma unroll 8
            for (int k = 0; k < 64; ++k) {
                float2 u = *(const float2*)&X[k * NSS + r0];
                float2 v = *(const float2*)&sT[k][c0];
                s00 += u.x * v.x; s01 += u.x * v.y;
                s10 += u.y * v.x; s11 += u.y * v.y;
            }
            float2 xo0 = *(const float2*)&X[r0 * NSS + c0];
            float2 xo1 = *(const float2*)&X[(r0 + 1) * NSS + c0];
            *(float2*)&Xn[r0 * NSS + c0]       = (float2){2.f * xo0.x - s00, 2.f * xo0.y - s01};
            *(float2*)&Xn[(r0 + 1) * NSS + c0] = (float2){2.f * xo1.x - s10, 2.f * xo1.y - s11};
        }
        __syncthreads();
        float* tmp = X; X = Xn; Xn = tmp;
    }
    for (int i = t; i < 4096; i += 1024)
        M[i] = X[(i >> 6) * NSS + (i & 63)];
}

// Per (b,k): mean = z[b, idx, :] @ M ; write bias; zero accumulators + cnt.
__global__ __launch_bounds__(64) void k_init(const float* __restrict__ z,
                                             const int* __restrict__ idxs,
                                             const float* __restrict__ M,
                                             const float* __restrict__ IA,
                                             float* __restrict__ out_mean,
                                             float* __restrict__ bias,
                                             float* __restrict__ nk,
                                             float* __restrict__ macc,
                                             int* __restrict__ cnt) {
    int k = blockIdx.x, b = blockIdx.y;
    int l = threadIdx.x;
    int bk = b * KK + k;
    __shared__ float srow[64];
    __shared__ float smean[64];
    int idx = idxs[bk];
    srow[l] = z[((size_t)b * NN + idx) * LL + l];
    __syncthreads();
    float nm = 0.f;
    #pragma unroll 8
    for (int m = 0; m < 64; ++m) nm += srow[m] * M[m * 64 + l];
    out_mean[(size_t)bk * LL + l] = nm;
    smean[l] = nm;
    __syncthreads();
    float cm = 0.f;
    #pragma unroll 8
    for (int m = 0; m < 64; ++m) cm += smean[m] * IA[m * 64 + l];
    float sqm = nm * nm;
    float sqc = cm * cm;
    for (int off = 32; off > 0; off >>= 1) {
        sqm += __shfl_down(sqm, off);
        sqc += __shfl_down(sqc, off);
    }
    if (l == 0) {
        bias[bk] = logf(1.0f / KK) - 0.5f * (sqm + sqc);
        nk[bk] = 0.f;
        if (k == 0) cnt[b] = 0;
    }
    macc[(size_t)bk * LL + l] = 0.f;
}

// Fused EM pass — exact r10 structure (best measured: 306.7 us total).
//  - 512 threads (8 waves); wave q owns zrows [16q,16q+16).
//  - register-direct phase-A staging (no z LDS for A); LDS 36 KB.
//  - launch_bounds(512,4): natural VGPR ~60; do NOT tighten further
//    ((512,8) pinned regs to 32 -> 226 MB spill traffic, r13).
//  - CHUNKS=8/NT=8: fewer, fatter blocks win — per-block fixed cost ~24 us
//    (r14: 1024 blocks at 2/CU ran 2 sequential generations, +30%).
__global__ __launch_bounds__(512, 4) void k_empass(const float* __restrict__ z,
                                                   float* __restrict__ mean,
                                                   float* __restrict__ bias,
                                                   float* __restrict__ nk,
                                                   float* __restrict__ macc,
                                                   int* __restrict__ cnt,
                                                   const float* __restrict__ M,
                                                   const float* __restrict__ IA,
                                                   float* __restrict__ out_pi,
                                                   float* __restrict__ out_trace) {
    __shared__ __align__(16) unsigned short mhl[2][32][ZSB];   // mean hi/lo, rows 20-31 zero
    __shared__ __align__(16) unsigned short zT[64][ZTS];       // z hi, [col][row]
    __shared__ __align__(16) unsigned short ptT[32][PTTS];     // posteriors [comp][zrow]
    __shared__ __align__(16) float bias_s[32];                 // comps >=20: -1e30
    __shared__ float nkred[8][KK];
    __shared__ int isLast;
    int t = threadIdx.x;
    int lane = t & 63;
    int q = t >> 6;             // wave id 0..7, owns zrows [16q,16q+16)
    int ln = lane & 15;
    int lg4 = lane >> 4;        // 0..3
    int b = blockIdx.y;
    size_t zbase = ((size_t)b * NN + (size_t)blockIdx.x * (TILE * NT)) * LL;
    int zr = q * 16 + ln;       // this thread's z row (tile-local)
    int fbase = zr * 16 + 2 * lg4;  // float4 index of first staged segment

    // ---- stage mean (hi/lo split) + zero pad rows + bias ----
    for (int i = t; i < KK * LL; i += 512) {
        float f = mean[(size_t)b * KK * LL + i];
        int k = i >> 6, c = i & 63;
        unsigned short h = f2bf(f);
        mhl[0][k][c] = h;
        mhl[1][k][c] = f2bf(f - bf2f(h));
    }
    for (int i = 20 * ZSB + t; i < 32 * ZSB; i += 512) {
        (&mhl[0][0][0])[i] = 0;
        (&mhl[1][0][0])[i] = 0;
    }
    if (t < 32) bias_s[t] = (t < KK) ? bias[b * KK + t] : -1e30f;

    const float4* zg = (const float4*)(z + zbase);
    float4 pf[4];
    // prologue: issue tile-0 loads (latency hides under mean staging)
    pf[0] = zg[fbase];
    pf[1] = zg[fbase + 1];
    pf[2] = zg[fbase + 8];
    pf[3] = zg[fbase + 9];
    __syncthreads();
    float4 b0 = *(const float4*)&bias_s[lg4 * 4];
    float4 b1 = *(const float4*)&bias_s[16 + lg4 * 4];
    // hoist mean fragments: [ks*4 + {mh0,ml0,mh1,ml1}]
    s16x8 mf[8];
    #pragma unroll
    for (int ks = 0; ks < 2; ++ks) {
        int kc = ks * 32 + lg4 * 8;
        mf[ks * 4 + 0] = *(const s16x8*)&mhl[0][ln][kc];
        mf[ks * 4 + 1] = *(const s16x8*)&mhl[1][ln][kc];
        mf[ks * 4 + 2] = *(const s16x8*)&mhl[0][16 + ln][kc];
        mf[ks * 4 + 3] = *(const s16x8*)&mhl[1][16 + ln][kc];
    }

    int ct = q & 3;                 // phase-B col-tile
    int chb = 2 * (q >> 2);         // phase-B row-chunk base (0 or 2)
    f32x4 bacc0 = {0.f, 0.f, 0.f, 0.f};
    f32x4 bacc1 = {0.f, 0.f, 0.f, 0.f};
    float nkp0[4] = {0.f, 0.f, 0.f, 0.f};
    float nkp1[4] = {0.f, 0.f, 0.f, 0.f};

    for (int tt = 0; tt < NT; ++tt) {
        // ---- convert staged regs -> bf16 hi/lo fragments (phase-A B-operand) ----
        s16x8 zh0, zl0, zh1, zl1;
        #pragma unroll
        for (int i = 0; i < 2; ++i) {
            float4 v = pf[i];
            float vv[4] = {v.x, v.y, v.z, v.w};
            #pragma unroll
            for (int j = 0; j < 4; ++j) {
                unsigned short h = f2bf(vv[j]);
                zh0[4 * i + j] = (short)h;
                zl0[4 * i + j] = (short)f2bf(vv[j] - bf2f(h));
            }
        }
        #pragma unroll
        for (int i = 0; i < 2; ++i) {
            float4 v = pf[2 + i];
            float vv[4] = {v.x, v.y, v.z, v.w};
            #pragma unroll
            for (int j = 0; j < 4; ++j) {
                unsigned short h = f2bf(vv[j]);
                zh1[4 * i + j] = (short)h;
                zl1[4 * i + j] = (short)f2bf(vv[j] - bf2f(h));
            }
        }
        // ---- issue next tile's loads (consumed after bar2) ----
        if (tt + 1 < NT) {
            size_t o = (size_t)(tt + 1) * 2048;
            pf[0] = zg[o + fbase];
            pf[1] = zg[o + fbase + 1];
            pf[2] = zg[o + fbase + 8];
            pf[3] = zg[o + fbase + 9];
        }
        // ---- write zT for current tile (window: after bar2(t-1), before bar1) ----
        #pragma unroll
        for (int e = 0; e < 8; ++e) {
            zT[8 * lg4 + e][zr]      = (unsigned short)zh0[e];
            zT[32 + 8 * lg4 + e][zr] = (unsigned short)zh1[e];
        }

        // ---- phase A: D[comp][zrow] = mean·zᵀ (3-product bf16 split) ----
        f32x4 acc0 = (f32x4){b0.x, b0.y, b0.z, b0.w};
        f32x4 acc1 = (f32x4){b1.x, b1.y, b1.z, b1.w};
        acc0 = MFMA_BF16(mf[0], zh0, acc0, 0, 0, 0);
        acc0 = MFMA_BF16(mf[1], zh0, acc0, 0, 0, 0);
        acc0 = MFMA_BF16(mf[0], zl0, acc0, 0, 0, 0);
        acc0 = MFMA_BF16(mf[4], zh1, acc0, 0, 0, 0);
        acc0 = MFMA_BF16(mf[5], zh1, acc0, 0, 0, 0);
        acc0 = MFMA_BF16(mf[4], zl1, acc0, 0, 0, 0);
        acc1 = MFMA_BF16(mf[2], zh0, acc1, 0, 0, 0);
        acc1 = MFMA_BF16(mf[3], zh0, acc1, 0, 0, 0);
        acc1 = MFMA_BF16(mf[2], zl0, acc1, 0, 0, 0);
        acc1 = MFMA_BF16(mf[6], zh1, acc1, 0, 0, 0);
        acc1 = MFMA_BF16(mf[7], zh1, acc1, 0, 0, 0);
        acc1 = MFMA_BF16(mf[6], zl1, acc1, 0, 0, 0);

        // ---- softmax over comps (regs + 2+2 shfls), branchless ----
        {
            float m = fmaxf(fmaxf(fmaxf(acc0[0], acc0[1]), fmaxf(acc0[2], acc0[3])),
                            fmaxf(fmaxf(acc1[0], acc1[1]), fmaxf(acc1[2], acc1[3])));
            m = fmaxf(m, __shfl_xor(m, 16));
            m = fmaxf(m, __shfl_xor(m, 32));
            float e0[4], e1[4];
            float sm = 0.f;
            #pragma unroll
            for (int j = 0; j < 4; ++j) {
                e0[j] = __expf(acc0[j] - m); sm += e0[j];
                e1[j] = __expf(acc1[j] - m); sm += e1[j];
            }
            sm += __shfl_xor(sm, 16);
            sm += __shfl_xor(sm, 32);
            float inv = 1.0f / sm;
            #pragma unroll
            for (int j = 0; j < 4; ++j) {
                float p0 = e0[j] * inv;
                float p1 = e1[j] * inv;
                nkp0[j] += p0;
                nkp1[j] += p1;
                ptT[lg4 * 4 + j][zr] = f2bf(p0);
                ptT[16 + lg4 * 4 + j][zr] = f2bf(p1);
            }
        }
        __syncthreads();    // bar1: ptT + zT complete

        // ---- phase B: D[comp][col] partial; wave q -> cols ct*16..+16 ----
        #pragma unroll
        for (int chi = 0; chi < 2; ++chi) {
            int rr = (chb + chi) * 32 + lg4 * 8;
            s16x8 zb  = *(const s16x8*)&zT[ct * 16 + ln][rr];
            s16x8 af0 = *(const s16x8*)&ptT[ln][rr];
            s16x8 af1 = *(const s16x8*)&ptT[16 + ln][rr];
            bacc0 = MFMA_BF16(af0, zb, bacc0, 0, 0, 0);
            bacc1 = MFMA_BF16(af1, zb, bacc1, 0, 0, 0);
        }
        __syncthreads();    // bar2: all B-reads done (consumed by MFMA pre-barrier)
    }

    // ---- Nk reduce: sum over ln lanes ----
    #pragma unroll
    for (int j = 0; j < 4; ++j) {
        nkp0[j] += __shfl_xor(nkp0[j], 1);
        nkp0[j] += __shfl_xor(nkp0[j], 2);
        nkp0[j] += __shfl_xor(nkp0[j], 4);
        nkp0[j] += __shfl_xor(nkp0[j], 8);
        nkp1[j] += __shfl_xor(nkp1[j], 1);
        nkp1[j] += __shfl_xor(nkp1[j], 2);
        nkp1[j] += __shfl_xor(nkp1[j], 4);
        nkp1[j] += __shfl_xor(nkp1[j], 8);
    }
    if (ln == 0) {
        #pragma unroll
        for (int j = 0; j < 4; ++j) nkred[q][lg4 * 4 + j] = nkp0[j];
        if (lg4 == 0) {
            #pragma unroll
            for (int j = 0; j < 4; ++j) nkred[q][16 + j] = nkp1[j];
        }
    }

    // ---- macc atomics: comp = 4lg4+reg (and 16+reg), col = 16ct+ln ----
    int col = ct * 16 + ln;
    #pragma unroll
    for (int reg = 0; reg < 4; ++reg) {
        int comp = lg4 * 4 + reg;
        atomicAdd(&macc[((size_t)b * KK + comp) * LL + col], bacc0[reg]);
    }
    if (lg4 == 0) {
        #pragma unroll
        for (int reg = 0; reg < 4; ++reg)
            atomicAdd(&macc[((size_t)b * KK + 16 + reg) * LL + col], bacc1[reg]);
    }
    __syncthreads();
    if (t < KK) {
        float sum = 0.f;
        #pragma unroll
        for (int w = 0; w < 8; ++w) sum += nkred[w][t];
        atomicAdd(&nk[b * KK + t], sum);
    }
    __syncthreads();            // all this block's atomics retired
    if (t == 0) {
        __threadfence();
        int old = atomicAdd(&cnt[b], 1);
        isLast = (old == CHUNKS - 1) ? 1 : 0;
    }
    __syncthreads();
    if (!isLast) return;

    // ---- finalize batch b (last block; waves 0-3 cover 20 comps) ----
    if (q < 4) {
        float* fs = (float*)&zT[0][0];
        float* sraw = fs + q * 160;
        float* smean = sraw + 64;
        int l = lane;
        #pragma unroll
        for (int kc5 = 0; kc5 < 5; ++kc5) {
            int comp = kc5 * 4 + q;
            int bk = b * KK + comp;
            size_t mb = (size_t)bk * LL;
            float nkv = 0.f;
            if (l == 0) nkv = atomicExch(&nk[bk], 0.f);
            nkv = __shfl(nkv, 0);
            float nkc = fmaxf(nkv, 1e-22f);
            float raw = atomicExch(&macc[mb + l], 0.f) / nkc;
            sraw[l] = raw;
            float nm = 0.f;
            #pragma unroll 8
            for (int m = 0; m < 64; ++m) nm += sraw[m] * M[m * 64 + l];
            mean[mb + l] = nm;
            smean[l] = nm;
            float cm = 0.f;
            #pragma unroll 8
            for (int m = 0; m < 64; ++m) cm += smean[m] * IA[m * 64 + l];
            float sqm = nm * nm;
            float sqc = cm * cm;
            #pragma unroll
            for (int off = 32; off > 0; off >>= 1) {
                sqm += __shfl_down(sqm, off);
                sqc += __shfl_down(sqc, off);
            }
            if (l == 0) {
                float pi = nkc * (1.0f / NN);
                bias[bk] = logf(pi) - 0.5f * (sqm + sqc);
                out_pi[bk] = pi;
                out_trace[bk] = 1.0f;
            }
        }
    }
    if (t == 0) cnt[b] = 0;
}

extern "C" void kernel_launch(void* const* d_in, const int* in_sizes, int n_in,
                              void* d_out, int out_size, void* d_ws, size_t ws_size,
                              hipStream_t stream) {
    const float* z = (const float*)d_in[0];
    const float* A = (const float*)d_in[1];
    const int* idxs = (const int*)d_in[2];

    float* out_pi = (float*)d_out;
    float* out_mean = out_pi + BB * KK;
    float* out_trace = out_mean + (size_t)BB * KK * LL;

    float* ws = (float*)d_ws;
    float* IA = ws;
    float* M = ws + 4096;
    float* bias = ws + 8192;
    float* nk = ws + 9472;
    float* macc = ws + 10752;
    int* cnt = (int*)(ws + 92672);

    k_setup<<<1, 1024, 0, stream>>>(A, IA, M);
    k_init<<<dim3(KK, BB), 64, 0, stream>>>(z, idxs, M, IA, out_mean, bias, nk, macc, cnt);
    for (int it = 0; it < 5; ++it) {
        k_empass<<<dim3(CHUNKS, BB), 512, 0, stream>>>(z, out_mean, bias, nk, macc,
                                                       cnt, M, IA, out_pi, out_trace);
    }
}